// Round 1
// baseline (110751.160 us; speedup 1.0000x reference)
//
#include <hip/hip_runtime.h>
#include <hip/hip_bf16.h>
#include <type_traits>

typedef __bf16 bf16_t;
typedef bf16_t bfx8 __attribute__((ext_vector_type(8)));
typedef bf16_t bfx4 __attribute__((ext_vector_type(4)));
typedef float  fx4  __attribute__((ext_vector_type(4)));

#define TT     256
#define BB     512
#define INDIM  512
#define NGENRE 5
#define HD     2048
#define LATD   1024
#define LATM   1019   // LAT - NG

// ---------- helpers ----------
__device__ __forceinline__ bf16_t f2b(float f) {
  unsigned u = __builtin_bit_cast(unsigned, f);
  u += 0x7fffu + ((u >> 16) & 1u);                // round-to-nearest-even
  unsigned short s = (unsigned short)(u >> 16);
  return __builtin_bit_cast(bf16_t, s);
}
__device__ __forceinline__ bf16_t to_bf(float v)  { return f2b(v); }
__device__ __forceinline__ bf16_t to_bf(bf16_t v) { return v; }
__device__ __forceinline__ float sigmoidf_(float x) { return 1.0f / (1.0f + __expf(-x)); }

// ---------- weight cast (fp32 -> bf16, K padded to mult of 32 with zeros) ----------
__global__ void wcast_pad(const float* __restrict__ src, bf16_t* __restrict__ dst,
                          int K, int ldp, int total /* rows*ldp */) {
  for (int i = blockIdx.x * 256 + threadIdx.x; i < total; i += gridDim.x * 256) {
    int r = i / ldp, c = i - r * ldp;
    dst[i] = (c < K) ? f2b(src[(size_t)r * K + c]) : f2b(0.0f);
  }
}

// ---------- fused GRU step ----------
// h_new = (1-z)*n + z*h ;  r=sig(gi_r+gh_r+b), z=sig(gi_z+gh_z+b), n=tanh(gi_n+b + r*(gh_n+b))
// gi = A1 @ Wih^T (phase 0, K1), gh = Hin @ Whh^T (phase 1, K=2048)
// Tile: 128 rows x 32 cols x 3 gate-rows. grid = 4*64 = 256 blocks, 256 threads.
// acc slots: 0=r(sum both phases) 1=z(sum) 2=inn(phase0 only) 3=hn(phase1 only)
template<typename WT>
__global__ __launch_bounds__(256, 1)
void gru_step(const float* __restrict__ A1, int lda1, int K1,
              const WT* __restrict__ Wih, int ldwih,
              const float* __restrict__ Hin,
              const WT* __restrict__ Whh, int ldwhh,
              const float* __restrict__ bih, const float* __restrict__ bhh,
              float* __restrict__ Hout)
{
  __shared__ bf16_t a_lds[128][32];
  __shared__ bf16_t b_lds[96][32];
  const int tid  = threadIdx.x;
  const int wave = tid >> 6, lane = tid & 63;
  const int m0 = (blockIdx.x >> 6) * 128;
  const int j0 = (blockIdx.x & 63) * 32;
  const int lr = lane & 15, lk = lane >> 4;

  fx4 acc[2][2][4];
#pragma unroll
  for (int a = 0; a < 2; ++a)
#pragma unroll
    for (int b = 0; b < 2; ++b)
#pragma unroll
      for (int g = 0; g < 4; ++g)
        acc[a][b][g] = fx4{0.f, 0.f, 0.f, 0.f};

  for (int ph = 0; ph < 2; ++ph) {
    const float* Ag = ph ? Hin : A1;
    const int lda   = ph ? HD : lda1;
    const int kLen  = ph ? HD : K1;
    const WT* W     = ph ? Whh : Wih;
    const int ldw   = ph ? ldwhh : ldwih;
    const int nslot = ph ? 3 : 2;
    const int nk    = (kLen + 31) >> 5;

    for (int s = 0; s < nk; ++s) {
      const int kb = s << 5;
      const bool full = (kb + 32 <= kLen);
      // ---- stage A tile 128x32 (fp32 -> bf16) ----
      if (Ag && full && ((lda & 3) == 0)) {
#pragma unroll
        for (int it = 0; it < 4; ++it) {
          int i = tid + it * 256;          // 1024 items: 128 rows x 8 float4
          int r = i >> 3, q = i & 7;
          const float4 v = *reinterpret_cast<const float4*>(&Ag[(size_t)(m0 + r) * lda + kb + q * 4]);
          bfx4 pk; pk[0] = f2b(v.x); pk[1] = f2b(v.y); pk[2] = f2b(v.z); pk[3] = f2b(v.w);
          *reinterpret_cast<bfx4*>(&a_lds[r][q * 4]) = pk;
        }
      } else {
#pragma unroll
        for (int it = 0; it < 16; ++it) {
          int i = tid + it * 256;          // 4096 items
          int r = i >> 5, kk = i & 31;
          int gk = kb + kk;
          float v = 0.0f;
          if (Ag && gk < kLen) v = Ag[(size_t)(m0 + r) * lda + gk];
          a_lds[r][kk] = f2b(v);
        }
      }
      // ---- stage B tile 96x32 : weight rows {j, H+j, 2H+j} ----
      if constexpr (std::is_same_v<WT, bf16_t>) {
        // padded bf16 weights: rows are ldw-strided, zero-filled past kLen; no k guard needed
        for (int i = tid; i < 384; i += 256) {   // 96 rows x 4 chunks of 8
          int r = i >> 2, ch = i & 3;
          int g = r >> 5, jj = r & 31;
          bfx8 v = *reinterpret_cast<const bfx8*>(&W[(size_t)(g * HD + j0 + jj) * ldw + kb + ch * 8]);
          *reinterpret_cast<bfx8*>(&b_lds[r][ch * 8]) = v;
        }
      } else {
#pragma unroll
        for (int it = 0; it < 12; ++it) {
          int i = tid + it * 256;          // 3072 items
          int r = i >> 5, kk = i & 31;
          int g = r >> 5, jj = r & 31;
          int gk = kb + kk;
          bf16_t v = f2b(0.0f);
          if (gk < kLen) v = to_bf(W[(size_t)(g * HD + j0 + jj) * ldw + gk]);
          b_lds[r][kk] = v;
        }
      }
      __syncthreads();
      // ---- fragments + MFMA ----
      bfx8 af[2];
#pragma unroll
      for (int fm = 0; fm < 2; ++fm)
        af[fm] = *reinterpret_cast<const bfx8*>(&a_lds[wave * 32 + fm * 16 + lr][lk * 8]);
#pragma unroll
      for (int g = 0; g < 3; ++g) {
        const int slot = (g == 2) ? nslot : g;
#pragma unroll
        for (int fj = 0; fj < 2; ++fj) {
          bfx8 bfrag = *reinterpret_cast<const bfx8*>(&b_lds[g * 32 + fj * 16 + lr][lk * 8]);
#pragma unroll
          for (int fm = 0; fm < 2; ++fm)
            acc[fm][fj][slot] = __builtin_amdgcn_mfma_f32_16x16x32_bf16(af[fm], bfrag, acc[fm][fj][slot], 0, 0, 0);
        }
      }
      __syncthreads();
    }
  }

  // ---- epilogue: gates + h update ----
#pragma unroll
  for (int fj = 0; fj < 2; ++fj) {
    const int col = j0 + fj * 16 + lr;
    const float br  = bih[col] + bhh[col];
    const float bz  = bih[HD + col] + bhh[HD + col];
    const float bin = bih[2 * HD + col];
    const float bhn = bhh[2 * HD + col];
#pragma unroll
    for (int fm = 0; fm < 2; ++fm) {
      const int rbase = m0 + wave * 32 + fm * 16 + lk * 4;
#pragma unroll
      for (int q = 0; q < 4; ++q) {
        const int row = rbase + q;
        const float r = sigmoidf_(acc[fm][fj][0][q] + br);
        const float z = sigmoidf_(acc[fm][fj][1][q] + bz);
        const float n = tanhf(acc[fm][fj][2][q] + bin + r * (acc[fm][fj][3][q] + bhn));
        const float hold = Hin[(size_t)row * HD + col];
        Hout[(size_t)row * HD + col] = (1.0f - z) * n + z * hold;
      }
    }
  }
}

// ---------- generic NT GEMM: O[M,N] = A[M,K] @ W[N,K]^T + bias ----------
// tile 64x64, 256 threads, waves 2x2 of 32x32. M must be mult of 64 (always 512 here).
template<typename WT>
__global__ __launch_bounds__(256, 1)
void gemm_nt(const float* __restrict__ A, int lda, int K,
             const WT* __restrict__ W, int ldw,
             const float* __restrict__ bias,
             float* __restrict__ O, int ldo, int N)
{
  __shared__ bf16_t a_lds[64][32];
  __shared__ bf16_t b_lds[64][32];
  const int tid  = threadIdx.x;
  const int wave = tid >> 6, lane = tid & 63;
  const int m0 = blockIdx.y * 64;
  const int n0 = blockIdx.x * 64;
  const int wm = (wave & 1) * 32, wn = (wave >> 1) * 32;
  const int lr = lane & 15, lk = lane >> 4;

  fx4 acc[2][2];
#pragma unroll
  for (int a = 0; a < 2; ++a)
#pragma unroll
    for (int b = 0; b < 2; ++b) acc[a][b] = fx4{0.f, 0.f, 0.f, 0.f};

  for (int kb = 0; kb < K; kb += 32) {
    // A: 64 rows x 8 float4 = 512 items (lda always mult of 4 here)
#pragma unroll
    for (int it = 0; it < 2; ++it) {
      int i = tid + it * 256;
      int r = i >> 3, q = i & 7;
      const float4 v = *reinterpret_cast<const float4*>(&A[(size_t)(m0 + r) * lda + kb + q * 4]);
      bfx4 pk; pk[0] = f2b(v.x); pk[1] = f2b(v.y); pk[2] = f2b(v.z); pk[3] = f2b(v.w);
      *reinterpret_cast<bfx4*>(&a_lds[r][q * 4]) = pk;
    }
    // B: 64 rows x 32
    if constexpr (std::is_same_v<WT, bf16_t>) {
      int r = tid >> 2, ch = tid & 3;            // 256 items exactly
      int n = n0 + r;
      bfx8 v;
#pragma unroll
      for (int e = 0; e < 8; ++e) v[e] = f2b(0.0f);
      if (n < N) v = *reinterpret_cast<const bfx8*>(&W[(size_t)n * ldw + kb + ch * 8]);
      *reinterpret_cast<bfx8*>(&b_lds[r][ch * 8]) = v;
    } else {
#pragma unroll
      for (int it = 0; it < 8; ++it) {
        int i = tid + it * 256;
        int r = i >> 5, kk = i & 31;
        int n = n0 + r;
        b_lds[r][kk] = (n < N) ? to_bf(W[(size_t)n * ldw + kb + kk]) : f2b(0.0f);
      }
    }
    __syncthreads();
    bfx8 af[2], bfr[2];
#pragma unroll
    for (int f = 0; f < 2; ++f) {
      af[f]  = *reinterpret_cast<const bfx8*>(&a_lds[wm + f * 16 + lr][lk * 8]);
      bfr[f] = *reinterpret_cast<const bfx8*>(&b_lds[wn + f * 16 + lr][lk * 8]);
    }
#pragma unroll
    for (int fm = 0; fm < 2; ++fm)
#pragma unroll
      for (int fj = 0; fj < 2; ++fj)
        acc[fm][fj] = __builtin_amdgcn_mfma_f32_16x16x32_bf16(af[fm], bfr[fj], acc[fm][fj], 0, 0, 0);
    __syncthreads();
  }

#pragma unroll
  for (int fm = 0; fm < 2; ++fm)
#pragma unroll
    for (int fj = 0; fj < 2; ++fj) {
      const int col = n0 + wn + fj * 16 + lr;
      if (col < N) {
        const float bb = bias[col];
#pragma unroll
        for (int q = 0; q < 4; ++q) {
          const int row = m0 + wm + fm * 16 + lk * 4 + q;
          O[(size_t)row * ldo + col] = acc[fm][fj][q] + bb;
        }
      }
    }
}

// ---------- z = [mu + exp(0.5*logvar)*eps , genre] ----------
__global__ void build_z(const float* __restrict__ mu, const float* __restrict__ lv,
                        const float* __restrict__ eps, const float* __restrict__ genre,
                        float* __restrict__ z) {
  int i = blockIdx.x * 256 + threadIdx.x;         // over BB*LATD
  int b = i >> 10, c = i & 1023;
  z[i] = (c < LATM) ? mu[(size_t)b * LATM + c] + expf(0.5f * lv[(size_t)b * LATM + c]) * eps[(size_t)b * LATM + c]
                    : genre[b * NGENRE + (c - LATM)];
}

// ---------- host ----------
template<typename WT>
static void run_all(const float* x, const float* genre, const float* eps,
                    const WT* eWih, int ldEih, const WT* eWhh, int ldEhh,
                    const float* eBih, const float* eBhh,
                    const WT* dWih, int ldDih, const WT* dWhh, int ldDhh,
                    const float* dBih, const float* dBhh,
                    const WT* fcMu, int ldMu, const float* fcMuB,
                    const WT* fcLv, const float* fcLvB,
                    const WT* fcOut, int ldOut, const float* fcOutB,
                    const WT* fcDec, int ldDec, const float* fcDecB,
                    float* out, float* muO, float* lvO,
                    float* h0, float* h1, float* zbuf, hipStream_t stream)
{
  float* hpp[2] = {h0, h1};
  hipMemsetAsync(h0, 0, (size_t)BB * HD * sizeof(float), stream);

  // encoder
  for (int t = 0; t < TT; ++t) {
    const float* xt = x + (size_t)t * BB * (INDIM + NGENRE);
    gru_step<WT><<<256, 256, 0, stream>>>(xt, INDIM + NGENRE, INDIM + NGENRE,
                                          eWih, ldEih, hpp[t & 1], eWhh, ldEhh,
                                          eBih, eBhh, hpp[(t & 1) ^ 1]);
  }
  // h_enc = hpp[0]
  dim3 gMu(16, 8);
  gemm_nt<WT><<<gMu, 256, 0, stream>>>(h0, HD, HD, fcMu, ldMu, fcMuB, muO, LATM, LATM);
  gemm_nt<WT><<<gMu, 256, 0, stream>>>(h0, HD, HD, fcLv, ldMu, fcLvB, lvO, LATM, LATM);
  build_z<<<(BB * LATD) / 256, 256, 0, stream>>>(muO, lvO, eps, genre, zbuf);
  dim3 gH0(32, 8);
  gemm_nt<WT><<<gH0, 256, 0, stream>>>(zbuf, LATD, LATD, fcOut, ldOut, fcOutB, h0, HD, HD);

  // decoder
  for (int t = 0; t < TT; ++t) {
    const float* noteprev = (t == 0) ? nullptr : out + (size_t)(t - 1) * BB * INDIM;
    gru_step<WT><<<256, 256, 0, stream>>>(noteprev, INDIM, INDIM,
                                          dWih, ldDih, hpp[t & 1], dWhh, ldDhh,
                                          dBih, dBhh, hpp[(t & 1) ^ 1]);
    dim3 gN(8, 8);
    gemm_nt<WT><<<gN, 256, 0, stream>>>(hpp[(t & 1) ^ 1], HD, HD, fcDec, ldDec, fcDecB,
                                        out + (size_t)t * BB * INDIM, INDIM, INDIM);
  }
}

extern "C" void kernel_launch(void* const* d_in, const int* in_sizes, int n_in,
                              void* d_out, int out_size, void* d_ws, size_t ws_size,
                              hipStream_t stream) {
  const float* x      = (const float*)d_in[0];
  const float* genre  = (const float*)d_in[1];
  const float* eps    = (const float*)d_in[2];
  const float* eWih   = (const float*)d_in[3];
  const float* eWhh   = (const float*)d_in[4];
  const float* eBih   = (const float*)d_in[5];
  const float* eBhh   = (const float*)d_in[6];
  const float* dWih   = (const float*)d_in[7];
  const float* dWhh   = (const float*)d_in[8];
  const float* dBih   = (const float*)d_in[9];
  const float* dBhh   = (const float*)d_in[10];
  const float* fcMuW  = (const float*)d_in[11];
  const float* fcMuB  = (const float*)d_in[12];
  const float* fcLvW  = (const float*)d_in[13];
  const float* fcLvB  = (const float*)d_in[14];
  const float* fcOutW = (const float*)d_in[15];
  const float* fcOutB = (const float*)d_in[16];
  const float* fcDecW = (const float*)d_in[17];
  const float* fcDecB = (const float*)d_in[18];

  float* out = (float*)d_out;
  float* muO = out + (size_t)TT * BB * INDIM;     // 67,108,864
  float* lvO = muO + (size_t)BB * LATM;           // +521,728

  // bf16 weight cache layout in ws (element offsets, K padded to mult of 32)
  const int ldEih = 544, ldEhh = 2048, ldDih = 512, ldDhh = 2048;
  const int ldMu = 2048, ldOut = 1024, ldDec = 2048;
  const size_t oEih = 0;
  const size_t oEhh = oEih + (size_t)3 * HD * ldEih;          //  3,342,336
  const size_t oDih = oEhh + (size_t)3 * HD * ldEhh;          // +12,582,912
  const size_t oDhh = oDih + (size_t)3 * HD * ldDih;
  const size_t oMu  = oDhh + (size_t)3 * HD * ldDhh;
  const size_t oLv  = oMu + (size_t)LATM * ldMu;
  const size_t oOut = oLv + (size_t)LATM * ldMu;
  const size_t oDec = oOut + (size_t)HD * ldOut;
  const size_t wElems = oDec + (size_t)INDIM * ldDec;         // 38,973,440
  const size_t bytesW = wElems * sizeof(bf16_t);
  const size_t needBf = bytesW + 2 * (size_t)BB * HD * 4 + (size_t)BB * LATD * 4;

  if (ws_size >= needBf) {
    bf16_t* wb = (bf16_t*)d_ws;
    char* after = (char*)d_ws + bytesW;
    float* h0 = (float*)after;
    float* h1 = h0 + (size_t)BB * HD;
    float* zb = h1 + (size_t)BB * HD;
    // cast all weights (every call — deterministic)
    auto cast = [&](const float* s, bf16_t* d, int rows, int K, int ldp) {
      int total = rows * ldp;
      int blocks = (total + 255) / 256; if (blocks > 4096) blocks = 4096;
      wcast_pad<<<blocks, 256, 0, stream>>>(s, d, K, ldp, total);
    };
    cast(eWih,   wb + oEih, 3 * HD, INDIM + NGENRE, ldEih);
    cast(eWhh,   wb + oEhh, 3 * HD, HD,   ldEhh);
    cast(dWih,   wb + oDih, 3 * HD, INDIM, ldDih);
    cast(dWhh,   wb + oDhh, 3 * HD, HD,   ldDhh);
    cast(fcMuW,  wb + oMu,  LATM,  HD,    ldMu);
    cast(fcLvW,  wb + oLv,  LATM,  HD,    ldMu);
    cast(fcOutW, wb + oOut, HD,    LATD,  ldOut);
    cast(fcDecW, wb + oDec, INDIM, HD,    ldDec);

    run_all<bf16_t>(x, genre, eps,
                    wb + oEih, ldEih, wb + oEhh, ldEhh, eBih, eBhh,
                    wb + oDih, ldDih, wb + oDhh, ldDhh, dBih, dBhh,
                    wb + oMu, ldMu, fcMuB, wb + oLv, fcLvB,
                    wb + oOut, ldOut, fcOutB, wb + oDec, ldDec, fcDecB,
                    out, muO, lvO, h0, h1, zb, stream);
  } else {
    // fp32-weight fallback (reads d_in weights directly, unpadded strides)
    float* h0 = (float*)d_ws;
    float* h1 = h0 + (size_t)BB * HD;
    float* zb = h1 + (size_t)BB * HD;
    run_all<float>(x, genre, eps,
                   eWih, INDIM + NGENRE, eWhh, HD, eBih, eBhh,
                   dWih, INDIM, dWhh, HD, dBih, dBhh,
                   fcMuW, HD, fcMuB, fcLvW, fcLvB,
                   fcOutW, LATD, fcOutB, fcDecW, HD, fcDecB,
                   out, muO, lvO, h0, h1, zb, stream);
  }
  (void)in_sizes; (void)n_in; (void)out_size;
}

// Round 2
// 33901.102 us; speedup vs baseline: 3.2669x; 3.2669x over previous
//
#include <hip/hip_runtime.h>
#include <hip/hip_bf16.h>

typedef __bf16 bf16_t;
typedef bf16_t bfx8 __attribute__((ext_vector_type(8)));
typedef bf16_t bfx4 __attribute__((ext_vector_type(4)));
typedef float  fx4  __attribute__((ext_vector_type(4)));

#define TT     256
#define BB     512
#define INDIM  512
#define NGENRE 5
#define HD     2048
#define LATD   1024
#define LATM   1019
#define XK     517     // IN + NG
#define XKP    576     // padded to x64

// ---------------- helpers ----------------
__device__ __forceinline__ bf16_t f2b(float f) {
  unsigned u = __builtin_bit_cast(unsigned, f);
  u += 0x7fffu + ((u >> 16) & 1u);
  unsigned short s = (unsigned short)(u >> 16);
  return __builtin_bit_cast(bf16_t, s);
}
__device__ __forceinline__ float sigmoidf_(float x) { return 1.0f / (1.0f + __expf(-x)); }

__device__ __forceinline__ void gload16(const bf16_t* g, bf16_t* l) {
  __builtin_amdgcn_global_load_lds((const __attribute__((address_space(1))) void*)g,
                                   (__attribute__((address_space(3))) void*)l,
                                   16, 0, 0);
}

// ---------------- fp32 -> bf16 cast with row/col zero-padding ----------------
__global__ void wcast_pad(const float* __restrict__ src, bf16_t* __restrict__ dst,
                          int rows_src, int rows_pad, int K, int ldp) {
  for (int r = blockIdx.x; r < rows_pad; r += gridDim.x)
    for (int c = threadIdx.x; c < ldp; c += 256)
      dst[(size_t)r * ldp + c] = (r < rows_src && c < K) ? f2b(src[(size_t)r * K + c]) : f2b(0.0f);
}

// ---------------- fused GRU step v2 ----------------
// Block: 128 rows x 32 cols (x3 gates), 256 thr (4 waves), wave = 32 rows x 32 cols.
// BK=64, double-buffered LDS staged via global_load_lds with st-style XOR swizzle.
// acc slots: 0=r 1=z 2=inn(phase0) 3=hn(phase1)
template<bool AF32>
__global__ __launch_bounds__(256, 1)
void gru2(const void* __restrict__ A1v, int lda1, int k1s, int K1,
          const bf16_t* __restrict__ Wih, int ldwih,
          const bf16_t* __restrict__ Hb,
          const bf16_t* __restrict__ Whh,
          const float* __restrict__ Hin,
          const float* __restrict__ bih, const float* __restrict__ bhh,
          float* __restrict__ Hout, bf16_t* __restrict__ HoutB)
{
  __shared__ bf16_t aT[2][128 * 64];
  __shared__ bf16_t bT[2][96 * 64];
  const int tid = threadIdx.x, wave = tid >> 6, lane = tid & 63;
  const int m0 = (blockIdx.x >> 6) * 128;
  const int j0 = (blockIdx.x & 63) * 32;
  const int lr = lane & 15, lk = lane >> 4;
  const int wm = wave;
  const int rl = lane >> 3;          // 0..7
  const int cl = (lane & 7) * 8;     // element chunk

  fx4 acc[2][2][4];
#pragma unroll
  for (int a = 0; a < 2; ++a)
#pragma unroll
    for (int b = 0; b < 2; ++b)
#pragma unroll
      for (int g = 0; g < 4; ++g) acc[a][b][g] = fx4{0.f, 0.f, 0.f, 0.f};

  // ---- precomputed per-lane staging addresses (src is inverse-swizzled) ----
  const bf16_t* A1b = (!AF32 && A1v) ? (const bf16_t*)A1v : Hb;  // dummy when null
  const float*  A1f = (const float*)A1v;
  const bf16_t* pA0[4]; const bf16_t* pA1[4];
  int aSlot[4];
#pragma unroll
  for (int i = 0; i < 4; ++i) {
    const int t = wave * 4 + i;
    const int r = t * 8 + rl;
    const int c = cl ^ ((r & 7) * 8);
    pA0[i] = A1b + (size_t)(m0 + r) * lda1 + c;
    pA1[i] = Hb  + (size_t)(m0 + r) * HD   + c;
    aSlot[i] = t * 512;
  }
  const bf16_t* pB0[3]; const bf16_t* pB1[3];
  int bSlot[3];
#pragma unroll
  for (int i = 0; i < 3; ++i) {
    const int t = wave * 3 + i;
    const int r = t * 8 + rl;
    const int g = r >> 5, jj = r & 31;
    const int c = cl ^ ((r & 7) * 8);
    pB0[i] = Wih + (size_t)(g * HD + j0 + jj) * ldwih + c;
    pB1[i] = Whh + (size_t)(g * HD + j0 + jj) * HD    + c;
    bSlot[i] = t * 512;
  }
  // ---- frag-read offsets (swizzled) ----
  int aRow[2], bRow[3][2], ko[2];
#pragma unroll
  for (int fm = 0; fm < 2; ++fm) aRow[fm] = (wm * 32 + fm * 16 + lr) * 64;
#pragma unroll
  for (int g = 0; g < 3; ++g)
#pragma unroll
    for (int fj = 0; fj < 2; ++fj) bRow[g][fj] = (g * 32 + fj * 16 + lr) * 64;
#pragma unroll
  for (int h = 0; h < 2; ++h) ko[h] = (h * 32 + lk * 8) ^ ((lr & 7) * 8);

  auto stage = [&](int buf, int s) {
    const int p  = (s >= k1s);
    const int kb = (p ? (s - k1s) : s) * 64;
    if (p) {
#pragma unroll
      for (int i = 0; i < 4; ++i) gload16(pA1[i] + kb, &aT[buf][aSlot[i]]);
    } else if constexpr (AF32) {
      // guarded fp32 -> bf16 scalar staging (encoder fallback path)
#pragma unroll
      for (int it = 0; it < 32; ++it) {
        int i = tid + it * 256;
        int r = i >> 6, c = i & 63;
        int gk = kb + c;
        float v = (gk < K1) ? A1f[(size_t)(m0 + r) * lda1 + gk] : 0.0f;
        aT[buf][r * 64 + (((c & ~7) ^ ((r & 7) * 8)) | (c & 7))] = f2b(v);
      }
    } else {
#pragma unroll
      for (int i = 0; i < 4; ++i) gload16(pA0[i] + kb, &aT[buf][aSlot[i]]);
    }
#pragma unroll
    for (int i = 0; i < 3; ++i)
      gload16((p ? pB1[i] : pB0[i]) + kb, &bT[buf][bSlot[i]]);
  };

  const int nk = k1s + HD / 64;
  stage(0, 0);
  __syncthreads();
  int cur = 0;
  for (int s = 0; s < nk; ++s) {
    if (s + 1 < nk) stage(cur ^ 1, s + 1);
    const int p = (s >= k1s);
    const bf16_t* aB = &aT[cur][0];
    const bf16_t* bB = &bT[cur][0];
#pragma unroll
    for (int h = 0; h < 2; ++h) {
      bfx8 af[2];
#pragma unroll
      for (int fm = 0; fm < 2; ++fm)
        af[fm] = *reinterpret_cast<const bfx8*>(&aB[aRow[fm] + ko[h]]);
#pragma unroll
      for (int g = 0; g < 3; ++g) {
        const int slot = (g == 2) ? (p ? 3 : 2) : g;
#pragma unroll
        for (int fj = 0; fj < 2; ++fj) {
          bfx8 bfr = *reinterpret_cast<const bfx8*>(&bB[bRow[g][fj] + ko[h]]);
#pragma unroll
          for (int fm = 0; fm < 2; ++fm)
            acc[fm][fj][slot] = __builtin_amdgcn_mfma_f32_16x16x32_bf16(af[fm], bfr, acc[fm][fj][slot], 0, 0, 0);
        }
      }
    }
    __syncthreads();
    cur ^= 1;
  }

  // ---- epilogue ----
#pragma unroll
  for (int fj = 0; fj < 2; ++fj) {
    const int col = j0 + fj * 16 + lr;
    const float br  = bih[col] + bhh[col];
    const float bz  = bih[HD + col] + bhh[HD + col];
    const float bin = bih[2 * HD + col];
    const float bhn = bhh[2 * HD + col];
#pragma unroll
    for (int fm = 0; fm < 2; ++fm) {
      const int rbase = m0 + wm * 32 + fm * 16 + lk * 4;
#pragma unroll
      for (int q = 0; q < 4; ++q) {
        const int row = rbase + q;
        const float r = sigmoidf_(acc[fm][fj][0][q] + br);
        const float z = sigmoidf_(acc[fm][fj][1][q] + bz);
        const float n = tanhf(acc[fm][fj][2][q] + bin + r * (acc[fm][fj][3][q] + bhn));
        const float hv = (1.0f - z) * n + z * Hin[(size_t)row * HD + col];
        Hout[(size_t)row * HD + col]  = hv;
        HoutB[(size_t)row * HD + col] = f2b(hv);
      }
    }
  }
}

// ---------------- bf16 NT GEMM v2 (gload_lds + swizzle + dbuf) ----------------
// O[M,N] = A[M,K] @ W[N,K]^T + bias ; tile 64x64, 256 thr. W rows padded to grid.
__global__ __launch_bounds__(256, 1)
void gemm_nt2(const bf16_t* __restrict__ A, int lda, int K,
              const bf16_t* __restrict__ W, int ldw,
              const float* __restrict__ bias,
              float* __restrict__ O, int ldo, int N,
              bf16_t* __restrict__ OB, int ldob)
{
  __shared__ bf16_t aT[2][64 * 64];
  __shared__ bf16_t bT[2][64 * 64];
  const int tid = threadIdx.x, wave = tid >> 6, lane = tid & 63;
  const int m0 = blockIdx.y * 64, n0 = blockIdx.x * 64;
  const int wm = wave & 1, wn = wave >> 1;
  const int lr = lane & 15, lk = lane >> 4;
  const int rl = lane >> 3, cl = (lane & 7) * 8;

  fx4 acc[2][2];
#pragma unroll
  for (int a = 0; a < 2; ++a)
#pragma unroll
    for (int b = 0; b < 2; ++b) acc[a][b] = fx4{0.f, 0.f, 0.f, 0.f};

  const bf16_t* pA[2]; const bf16_t* pB[2]; int slot[2];
#pragma unroll
  for (int i = 0; i < 2; ++i) {
    const int t = wave * 2 + i;
    const int r = t * 8 + rl;
    const int c = cl ^ ((r & 7) * 8);
    pA[i] = A + (size_t)(m0 + r) * lda + c;
    pB[i] = W + (size_t)(n0 + r) * ldw + c;
    slot[i] = t * 512;
  }
  int aRow[2], bRow[2], ko[2];
#pragma unroll
  for (int f = 0; f < 2; ++f) {
    aRow[f] = (wm * 32 + f * 16 + lr) * 64;
    bRow[f] = (wn * 32 + f * 16 + lr) * 64;
  }
#pragma unroll
  for (int h = 0; h < 2; ++h) ko[h] = (h * 32 + lk * 8) ^ ((lr & 7) * 8);

  auto stage = [&](int buf, int kb) {
#pragma unroll
    for (int i = 0; i < 2; ++i) {
      gload16(pA[i] + kb, &aT[buf][slot[i]]);
      gload16(pB[i] + kb, &bT[buf][slot[i]]);
    }
  };

  const int nk = K >> 6;
  stage(0, 0);
  __syncthreads();
  int cur = 0;
  for (int s = 0; s < nk; ++s) {
    if (s + 1 < nk) stage(cur ^ 1, (s + 1) << 6);
    const bf16_t* aB = &aT[cur][0];
    const bf16_t* bB = &bT[cur][0];
#pragma unroll
    for (int h = 0; h < 2; ++h) {
      bfx8 af[2], bf[2];
#pragma unroll
      for (int f = 0; f < 2; ++f) {
        af[f] = *reinterpret_cast<const bfx8*>(&aB[aRow[f] + ko[h]]);
        bf[f] = *reinterpret_cast<const bfx8*>(&bB[bRow[f] + ko[h]]);
      }
#pragma unroll
      for (int fm = 0; fm < 2; ++fm)
#pragma unroll
        for (int fj = 0; fj < 2; ++fj)
          acc[fm][fj] = __builtin_amdgcn_mfma_f32_16x16x32_bf16(af[fm], bf[fj], acc[fm][fj], 0, 0, 0);
    }
    __syncthreads();
    cur ^= 1;
  }

#pragma unroll
  for (int fm = 0; fm < 2; ++fm)
#pragma unroll
    for (int fj = 0; fj < 2; ++fj) {
      const int col = n0 + wn * 32 + fj * 16 + lr;
      if (col < N) {
        const float bb = bias[col];
#pragma unroll
        for (int q = 0; q < 4; ++q) {
          const int row = m0 + wm * 32 + fm * 16 + lk * 4 + q;
          const float v = acc[fm][fj][q] + bb;
          O[(size_t)row * ldo + col] = v;
          if (OB) OB[(size_t)row * ldob + col] = f2b(v);
        }
      }
    }
}

// ---------------- z build (writes bf16) ----------------
__global__ void build_zb(const float* __restrict__ mu, const float* __restrict__ lv,
                         const float* __restrict__ eps, const float* __restrict__ genre,
                         bf16_t* __restrict__ zb) {
  int i = blockIdx.x * 256 + threadIdx.x;   // BB*LATD
  int b = i >> 10, c = i & 1023;
  float v;
  if (c < LATM) {
    size_t k = (size_t)b * LATM + c;
    v = mu[k] + expf(0.5f * lv[k]) * eps[k];
  } else {
    v = genre[b * NGENRE + (c - LATM)];
  }
  zb[i] = f2b(v);
}

// ================= fp32 fallback (round-1 kernels, float weights) =================
__global__ __launch_bounds__(256, 1)
void gru_stepF(const float* __restrict__ A1, int lda1, int K1,
               const float* __restrict__ Wih,
               const float* __restrict__ Hin,
               const float* __restrict__ Whh,
               const float* __restrict__ bih, const float* __restrict__ bhh,
               float* __restrict__ Hout)
{
  __shared__ bf16_t a_lds[128][32];
  __shared__ bf16_t b_lds[96][32];
  const int tid = threadIdx.x, wave = tid >> 6, lane = tid & 63;
  const int m0 = (blockIdx.x >> 6) * 128, j0 = (blockIdx.x & 63) * 32;
  const int lr = lane & 15, lk = lane >> 4;
  fx4 acc[2][2][4];
#pragma unroll
  for (int a = 0; a < 2; ++a)
#pragma unroll
    for (int b = 0; b < 2; ++b)
#pragma unroll
      for (int g = 0; g < 4; ++g) acc[a][b][g] = fx4{0.f, 0.f, 0.f, 0.f};

  for (int ph = 0; ph < 2; ++ph) {
    const float* Ag = ph ? Hin : A1;
    const int lda = ph ? HD : lda1, kLen = ph ? HD : K1;
    const float* W = ph ? Whh : Wih;
    const int nslot = ph ? 3 : 2;
    const int nkk = (kLen + 31) >> 5;
    for (int s = 0; s < nkk; ++s) {
      const int kb = s << 5;
#pragma unroll
      for (int it = 0; it < 16; ++it) {
        int i = tid + it * 256;
        int r = i >> 5, kk = i & 31, gk = kb + kk;
        float v = 0.0f;
        if (Ag && gk < kLen) v = Ag[(size_t)(m0 + r) * lda + gk];
        a_lds[r][kk] = f2b(v);
      }
#pragma unroll
      for (int it = 0; it < 12; ++it) {
        int i = tid + it * 256;
        int r = i >> 5, kk = i & 31, g = r >> 5, jj = r & 31, gk = kb + kk;
        b_lds[r][kk] = (gk < kLen) ? f2b(W[(size_t)(g * HD + j0 + jj) * kLen + gk]) : f2b(0.0f);
      }
      __syncthreads();
      bfx8 af[2];
#pragma unroll
      for (int fm = 0; fm < 2; ++fm)
        af[fm] = *reinterpret_cast<const bfx8*>(&a_lds[wave * 32 + fm * 16 + lr][lk * 8]);
#pragma unroll
      for (int g = 0; g < 3; ++g) {
        const int slot = (g == 2) ? nslot : g;
#pragma unroll
        for (int fj = 0; fj < 2; ++fj) {
          bfx8 bfr = *reinterpret_cast<const bfx8*>(&b_lds[g * 32 + fj * 16 + lr][lk * 8]);
#pragma unroll
          for (int fm = 0; fm < 2; ++fm)
            acc[fm][fj][slot] = __builtin_amdgcn_mfma_f32_16x16x32_bf16(af[fm], bfr, acc[fm][fj][slot], 0, 0, 0);
        }
      }
      __syncthreads();
    }
  }
#pragma unroll
  for (int fj = 0; fj < 2; ++fj) {
    const int col = j0 + fj * 16 + lr;
    const float br = bih[col] + bhh[col];
    const float bz = bih[HD + col] + bhh[HD + col];
    const float bin = bih[2 * HD + col];
    const float bhn = bhh[2 * HD + col];
#pragma unroll
    for (int fm = 0; fm < 2; ++fm) {
      const int rbase = m0 + wave * 32 + fm * 16 + lk * 4;
#pragma unroll
      for (int q = 0; q < 4; ++q) {
        const int row = rbase + q;
        const float r = sigmoidf_(acc[fm][fj][0][q] + br);
        const float z = sigmoidf_(acc[fm][fj][1][q] + bz);
        const float n = tanhf(acc[fm][fj][2][q] + bin + r * (acc[fm][fj][3][q] + bhn));
        Hout[(size_t)row * HD + col] = (1.0f - z) * n + z * Hin[(size_t)row * HD + col];
      }
    }
  }
}

__global__ __launch_bounds__(256, 1)
void gemm_ntF(const float* __restrict__ A, int lda, int K,
              const float* __restrict__ W,
              const float* __restrict__ bias,
              float* __restrict__ O, int ldo, int N)
{
  __shared__ bf16_t a_lds[64][32];
  __shared__ bf16_t b_lds[64][32];
  const int tid = threadIdx.x, wave = tid >> 6, lane = tid & 63;
  const int m0 = blockIdx.y * 64, n0 = blockIdx.x * 64;
  const int wm = (wave & 1) * 32, wn = (wave >> 1) * 32;
  const int lr = lane & 15, lk = lane >> 4;
  fx4 acc[2][2];
#pragma unroll
  for (int a = 0; a < 2; ++a)
#pragma unroll
    for (int b = 0; b < 2; ++b) acc[a][b] = fx4{0.f, 0.f, 0.f, 0.f};
  for (int kb = 0; kb < K; kb += 32) {
#pragma unroll
    for (int it = 0; it < 8; ++it) {
      int i = tid + it * 256;
      int r = i >> 5, kk = i & 31;
      a_lds[r][kk] = f2b(A[(size_t)(m0 + r) * lda + kb + kk]);
    }
#pragma unroll
    for (int it = 0; it < 8; ++it) {
      int i = tid + it * 256;
      int r = i >> 5, kk = i & 31;
      int n = n0 + r;
      b_lds[r][kk] = (n < N) ? f2b(W[(size_t)n * K + kb + kk]) : f2b(0.0f);
    }
    __syncthreads();
    bfx8 af[2], bfr[2];
#pragma unroll
    for (int f = 0; f < 2; ++f) {
      af[f] = *reinterpret_cast<const bfx8*>(&a_lds[wm + f * 16 + lr][lk * 8]);
      bfr[f] = *reinterpret_cast<const bfx8*>(&b_lds[wn + f * 16 + lr][lk * 8]);
    }
#pragma unroll
    for (int fm = 0; fm < 2; ++fm)
#pragma unroll
      for (int fj = 0; fj < 2; ++fj)
        acc[fm][fj] = __builtin_amdgcn_mfma_f32_16x16x32_bf16(af[fm], bfr[fj], acc[fm][fj], 0, 0, 0);
    __syncthreads();
  }
#pragma unroll
  for (int fm = 0; fm < 2; ++fm)
#pragma unroll
    for (int fj = 0; fj < 2; ++fj) {
      const int col = n0 + wn + fj * 16 + lr;
      if (col < N) {
        const float bb = bias[col];
#pragma unroll
        for (int q = 0; q < 4; ++q) {
          const int row = m0 + wm + fm * 16 + lk * 4 + q;
          O[(size_t)row * ldo + col] = acc[fm][fj][q] + bb;
        }
      }
    }
}

__global__ void build_zf(const float* __restrict__ mu, const float* __restrict__ lv,
                         const float* __restrict__ eps, const float* __restrict__ genre,
                         float* __restrict__ z) {
  int i = blockIdx.x * 256 + threadIdx.x;
  int b = i >> 10, c = i & 1023;
  z[i] = (c < LATM) ? mu[(size_t)b * LATM + c] + expf(0.5f * lv[(size_t)b * LATM + c]) * eps[(size_t)b * LATM + c]
                    : genre[b * NGENRE + (c - LATM)];
}

// ---------------- host ----------------
extern "C" void kernel_launch(void* const* d_in, const int* in_sizes, int n_in,
                              void* d_out, int out_size, void* d_ws, size_t ws_size,
                              hipStream_t stream) {
  const float* x      = (const float*)d_in[0];
  const float* genre  = (const float*)d_in[1];
  const float* eps    = (const float*)d_in[2];
  const float* eWih   = (const float*)d_in[3];
  const float* eWhh   = (const float*)d_in[4];
  const float* eBih   = (const float*)d_in[5];
  const float* eBhh   = (const float*)d_in[6];
  const float* dWih   = (const float*)d_in[7];
  const float* dWhh   = (const float*)d_in[8];
  const float* dBih   = (const float*)d_in[9];
  const float* dBhh   = (const float*)d_in[10];
  const float* fcMuW  = (const float*)d_in[11];
  const float* fcMuB  = (const float*)d_in[12];
  const float* fcLvW  = (const float*)d_in[13];
  const float* fcLvB  = (const float*)d_in[14];
  const float* fcOutW = (const float*)d_in[15];
  const float* fcOutB = (const float*)d_in[16];
  const float* fcDecW = (const float*)d_in[17];
  const float* fcDecB = (const float*)d_in[18];

  float* out = (float*)d_out;
  float* muO = out + (size_t)TT * BB * INDIM;
  float* lvO = muO + (size_t)BB * LATM;

  // bf16 weight layout (element offsets)
  const size_t nEih = (size_t)3 * HD * XKP;
  const size_t nEhh = (size_t)3 * HD * HD;
  const size_t nDih = (size_t)3 * HD * INDIM;
  const size_t nDhh = (size_t)3 * HD * HD;
  const size_t nMu  = (size_t)1024 * HD;
  const size_t nOut = (size_t)HD * LATD;
  const size_t nDec = (size_t)INDIM * HD;
  const size_t oEih = 0;
  const size_t oEhh = oEih + nEih;
  const size_t oDih = oEhh + nEhh;
  const size_t oDhh = oDih + nDih;
  const size_t oMu  = oDhh + nDhh;
  const size_t oLv  = oMu + nMu;
  const size_t oOut = oLv + nMu;
  const size_t oDec = oOut + nOut;
  const size_t wTot = oDec + nDec;

  const size_t bytesW  = wTot * 2;
  const size_t bytesHF = (size_t)BB * HD * 4;
  const size_t bytesHB = (size_t)BB * HD * 2;
  const size_t bytesZB = (size_t)BB * LATD * 2;
  const size_t bytesNB = (size_t)BB * INDIM * 2;
  const size_t bytesXB = (size_t)TT * BB * XKP * 2;
  const size_t needB   = bytesW + 2 * bytesHF + 2 * bytesHB + bytesZB + bytesNB + 1024;
  const size_t needA   = needB + bytesXB;

  if (ws_size >= needB) {
    const bool haveXB = (ws_size >= needA);
    char* p = (char*)d_ws;
    bf16_t* wb = (bf16_t*)p;            p += bytesW;
    float* h0  = (float*)p;             p += bytesHF;
    float* h1  = (float*)p;             p += bytesHF;
    bf16_t* hb0 = (bf16_t*)p;           p += bytesHB;
    bf16_t* hb1 = (bf16_t*)p;           p += bytesHB;
    bf16_t* zb  = (bf16_t*)p;           p += bytesZB;
    bf16_t* nb  = (bf16_t*)p;           p += bytesNB;
    bf16_t* xb  = haveXB ? (bf16_t*)p : nullptr;

    auto cast = [&](const float* s, bf16_t* d, int rs, int rp, int K, int ldp) {
      int g = rp > 8192 ? 8192 : rp;
      wcast_pad<<<g, 256, 0, stream>>>(s, d, rs, rp, K, ldp);
    };
    cast(eWih,   wb + oEih, 3 * HD, 3 * HD, XK,    XKP);
    cast(eWhh,   wb + oEhh, 3 * HD, 3 * HD, HD,    HD);
    cast(dWih,   wb + oDih, 3 * HD, 3 * HD, INDIM, INDIM);
    cast(dWhh,   wb + oDhh, 3 * HD, 3 * HD, HD,    HD);
    cast(fcMuW,  wb + oMu,  LATM,   1024,   HD,    HD);
    cast(fcLvW,  wb + oLv,  LATM,   1024,   HD,    HD);
    cast(fcOutW, wb + oOut, HD,     HD,     LATD,  LATD);
    cast(fcDecW, wb + oDec, INDIM,  INDIM,  HD,    HD);
    if (haveXB) cast(x, xb, TT * BB, TT * BB, XK, XKP);

    hipMemsetAsync(h0, 0, bytesHF, stream);
    hipMemsetAsync(hb0, 0, bytesHB, stream);

    float*  hF[2] = {h0, h1};
    bf16_t* hB[2] = {hb0, hb1};

    // ---- encoder ----
    for (int t = 0; t < TT; ++t) {
      const int ci = t & 1, co = ci ^ 1;
      if (haveXB) {
        gru2<false><<<256, 256, 0, stream>>>(xb + (size_t)t * BB * XKP, XKP, XKP / 64, XKP,
                                             wb + oEih, XKP, hB[ci], wb + oEhh,
                                             hF[ci], eBih, eBhh, hF[co], hB[co]);
      } else {
        gru2<true><<<256, 256, 0, stream>>>(x + (size_t)t * BB * XK, XK, XKP / 64, XK,
                                            wb + oEih, XKP, hB[ci], wb + oEhh,
                                            hF[ci], eBih, eBhh, hF[co], hB[co]);
      }
    }
    // h_enc = hF[0]/hB[0]
    gemm_nt2<<<dim3(16, 8), 256, 0, stream>>>(hB[0], HD, HD, wb + oMu, HD, fcMuB,
                                              muO, LATM, LATM, nullptr, 0);
    gemm_nt2<<<dim3(16, 8), 256, 0, stream>>>(hB[0], HD, HD, wb + oLv, HD, fcLvB,
                                              lvO, LATM, LATM, nullptr, 0);
    build_zb<<<(BB * LATD) / 256, 256, 0, stream>>>(muO, lvO, eps, genre, zb);
    gemm_nt2<<<dim3(32, 8), 256, 0, stream>>>(zb, LATD, LATD, wb + oOut, LATD, fcOutB,
                                              hF[0], HD, HD, hB[0], HD);
    // ---- decoder ----
    for (int t = 0; t < TT; ++t) {
      const int ci = t & 1, co = ci ^ 1;
      gru2<false><<<256, 256, 0, stream>>>(t ? (const void*)nb : nullptr, INDIM,
                                           t ? INDIM / 64 : 0, INDIM,
                                           wb + oDih, INDIM, hB[ci], wb + oDhh,
                                           hF[ci], dBih, dBhh, hF[co], hB[co]);
      gemm_nt2<<<dim3(8, 8), 256, 0, stream>>>(hB[co], HD, HD, wb + oDec, HD, fcDecB,
                                               out + (size_t)t * BB * INDIM, INDIM, INDIM,
                                               nb, INDIM);
    }
  } else {
    // ---- fp32 fallback ----
    float* h0 = (float*)d_ws;
    float* h1 = h0 + (size_t)BB * HD;
    float* zb = h1 + (size_t)BB * HD;
    hipMemsetAsync(h0, 0, (size_t)BB * HD * sizeof(float), stream);
    float* hF[2] = {h0, h1};
    for (int t = 0; t < TT; ++t) {
      const int ci = t & 1, co = ci ^ 1;
      gru_stepF<<<256, 256, 0, stream>>>(x + (size_t)t * BB * XK, XK, XK, eWih,
                                         hF[ci], eWhh, eBih, eBhh, hF[co]);
    }
    gemm_ntF<<<dim3(16, 8), 256, 0, stream>>>(hF[0], HD, HD, fcMuW, fcMuB, muO, LATM, LATM);
    gemm_ntF<<<dim3(16, 8), 256, 0, stream>>>(hF[0], HD, HD, fcLvW, fcLvB, lvO, LATM, LATM);
    build_zf<<<(BB * LATD) / 256, 256, 0, stream>>>(muO, lvO, eps, genre, zb);
    gemm_ntF<<<dim3(32, 8), 256, 0, stream>>>(zb, LATD, LATD, fcOutW, fcOutB, hF[0], HD, HD);
    for (int t = 0; t < TT; ++t) {
      const int ci = t & 1, co = ci ^ 1;
      gru_stepF<<<256, 256, 0, stream>>>(t ? out + (size_t)(t - 1) * BB * INDIM : nullptr,
                                         INDIM, INDIM, dWih, hF[ci], dWhh, dBih, dBhh, hF[co]);
      gemm_ntF<<<dim3(8, 8), 256, 0, stream>>>(hF[co], HD, HD, fcDecW, fcDecB,
                                               out + (size_t)t * BB * INDIM, INDIM, INDIM);
    }
  }
  (void)in_sizes; (void)n_in; (void)out_size;
}

// Round 3
// 21397.440 us; speedup vs baseline: 5.1759x; 1.5844x over previous
//
#include <hip/hip_runtime.h>
#include <hip/hip_bf16.h>

typedef __bf16 bf16_t;
typedef bf16_t bfx8 __attribute__((ext_vector_type(8)));
typedef float  fx4  __attribute__((ext_vector_type(4)));

#define TT     256
#define BB     512
#define INDIM  512
#define NGENRE 5
#define HD     2048
#define LATD   1024
#define LATM   1019
#define XK     517
#define XKP    576

// ---------------- helpers ----------------
__device__ __forceinline__ bf16_t f2b(float f) {
  unsigned u = __builtin_bit_cast(unsigned, f);
  u += 0x7fffu + ((u >> 16) & 1u);
  unsigned short s = (unsigned short)(u >> 16);
  return __builtin_bit_cast(bf16_t, s);
}
__device__ __forceinline__ float sigmoidf_(float x) { return 1.0f / (1.0f + __expf(-x)); }

__device__ __forceinline__ void gload16(const bf16_t* g, bf16_t* l) {
  __builtin_amdgcn_global_load_lds((const __attribute__((address_space(1))) void*)g,
                                   (__attribute__((address_space(3))) void*)l,
                                   16, 0, 0);
}
__device__ __forceinline__ void wait_vm0() { asm volatile("s_waitcnt vmcnt(0)" ::: "memory"); }
__device__ __forceinline__ void wait_vm4() { asm volatile("s_waitcnt vmcnt(4)" ::: "memory"); }
__device__ __forceinline__ void wait_vm5() { asm volatile("s_waitcnt vmcnt(5)" ::: "memory"); }
__device__ __forceinline__ void wait_lgkm0() { asm volatile("s_waitcnt lgkmcnt(0)" ::: "memory"); }

// ---------------- fp32 -> bf16 cast with row/col zero-padding ----------------
__global__ void wcast_pad(const float* __restrict__ src, bf16_t* __restrict__ dst,
                          int rows_src, int rows_pad, int K, int ldp) {
  for (int r = blockIdx.x; r < rows_pad; r += gridDim.x)
    for (int c = threadIdx.x; c < ldp; c += 256)
      dst[(size_t)r * ldp + c] = (r < rows_src && c < K) ? f2b(src[(size_t)r * K + c]) : f2b(0.0f);
}

// ---------------- fused GRU step v3: counted-vmcnt pipeline ----------------
// Block: 64 rows x 32 j-cols (x3 gates), 256 thr, grid 512 (2 blocks/CU).
// Wave w owns rows [w*16, w*16+16). BK=64, depth-2 prefetch, 5 gload_lds/stage.
// acc slots: 0=r 1=z 2=inn(phase0) 3=hn(phase1)
__global__ __launch_bounds__(256, 2)
void gru3(const bf16_t* __restrict__ A1, int lda1, int k1s,
          const bf16_t* __restrict__ Wih, int ldwih,
          const bf16_t* __restrict__ Hb,
          const bf16_t* __restrict__ Whh,
          const float* __restrict__ Hin,
          const float* __restrict__ bih, const float* __restrict__ bhh,
          float* __restrict__ Hout, bf16_t* __restrict__ HoutB)
{
  __shared__ bf16_t aT[2][64 * 64];
  __shared__ bf16_t bT[2][96 * 64];
  const int tid = threadIdx.x, wave = tid >> 6, lane = tid & 63;
  const int m0 = (blockIdx.x >> 6) * 64;
  const int j0 = (blockIdx.x & 63) * 32;
  const int lr = lane & 15, lk = lane >> 4;
  const int rl = lane >> 3;          // 0..7
  const int cl = (lane & 7) * 8;     // element chunk

  fx4 acc[2][4];
#pragma unroll
  for (int b = 0; b < 2; ++b)
#pragma unroll
    for (int g = 0; g < 4; ++g) acc[b][g] = fx4{0.f, 0.f, 0.f, 0.f};

  // staging source pointers (global col pre-swizzled; LDS dest linear)
  const bf16_t* A1b = A1 ? A1 : Hb;
  const bf16_t* pA0[2]; const bf16_t* pA1[2]; int aSlot[2];
#pragma unroll
  for (int i = 0; i < 2; ++i) {
    const int t = wave * 2 + i;
    const int r = t * 8 + rl;                  // 0..63
    const int c = cl ^ ((r & 7) * 8);
    pA0[i] = A1b + (size_t)(m0 + r) * lda1 + c;
    pA1[i] = Hb  + (size_t)(m0 + r) * HD   + c;
    aSlot[i] = t * 512;
  }
  const bf16_t* pB0[3]; const bf16_t* pB1[3]; int bSlot[3];
#pragma unroll
  for (int i = 0; i < 3; ++i) {
    const int t = wave * 3 + i;
    const int r = t * 8 + rl;                  // 0..95
    const int g = r >> 5, jj = r & 31;
    const int c = cl ^ ((r & 7) * 8);
    pB0[i] = Wih + (size_t)(g * HD + j0 + jj) * ldwih + c;
    pB1[i] = Whh + (size_t)(g * HD + j0 + jj) * HD    + c;
    bSlot[i] = t * 512;
  }
  // fragment read offsets (swizzled)
  int aRow, bRow[3][2], ko[2];
  aRow = (wave * 16 + lr) * 64;
#pragma unroll
  for (int g = 0; g < 3; ++g)
#pragma unroll
    for (int fj = 0; fj < 2; ++fj) bRow[g][fj] = (g * 32 + fj * 16 + lr) * 64;
#pragma unroll
  for (int h = 0; h < 2; ++h) ko[h] = (h * 32 + lk * 8) ^ ((lr & 7) * 8);

  auto stage = [&](int buf, int s) {
    const int p  = (s >= k1s);
    const int kb = (p ? (s - k1s) : s) * 64;
    if (p) {
#pragma unroll
      for (int i = 0; i < 2; ++i) gload16(pA1[i] + kb, &aT[buf][aSlot[i]]);
#pragma unroll
      for (int i = 0; i < 3; ++i) gload16(pB1[i] + kb, &bT[buf][bSlot[i]]);
    } else {
#pragma unroll
      for (int i = 0; i < 2; ++i) gload16(pA0[i] + kb, &aT[buf][aSlot[i]]);
#pragma unroll
      for (int i = 0; i < 3; ++i) gload16(pB0[i] + kb, &bT[buf][bSlot[i]]);
    }
  };

  const int nk = k1s + HD / 64;
  stage(0, 0);
  stage(1, 1);
  for (int s = 0; s < nk; ++s) {
    if (s == nk - 1) wait_vm0(); else wait_vm5();
    __builtin_amdgcn_s_barrier();            // tile s fully in LDS (all waves)
    const bf16_t* aB = &aT[s & 1][0];
    const bf16_t* bB = &bT[s & 1][0];
    bfx8 af[2]; bfx8 bfr[3][2][2];
#pragma unroll
    for (int h = 0; h < 2; ++h)
      af[h] = *reinterpret_cast<const bfx8*>(&aB[aRow + ko[h]]);
#pragma unroll
    for (int g = 0; g < 3; ++g)
#pragma unroll
      for (int fj = 0; fj < 2; ++fj)
#pragma unroll
        for (int h = 0; h < 2; ++h)
          bfr[g][fj][h] = *reinterpret_cast<const bfx8*>(&bB[bRow[g][fj] + ko[h]]);
    wait_lgkm0();
    __builtin_amdgcn_sched_barrier(0);
    __builtin_amdgcn_s_barrier();            // all waves done reading buf
    if (s + 2 < nk) stage(s & 1, s + 2);     // overwrite read-done buffer
    const int p = (s >= k1s);
    __builtin_amdgcn_s_setprio(1);
#pragma unroll
    for (int h = 0; h < 2; ++h)
#pragma unroll
      for (int g = 0; g < 3; ++g) {
        const int slot = (g == 2) ? (p ? 3 : 2) : g;
#pragma unroll
        for (int fj = 0; fj < 2; ++fj)
          acc[fj][slot] = __builtin_amdgcn_mfma_f32_16x16x32_bf16(af[h], bfr[g][fj][h], acc[fj][slot], 0, 0, 0);
      }
    __builtin_amdgcn_s_setprio(0);
  }

  // ---- epilogue: gates + h update ----
#pragma unroll
  for (int fj = 0; fj < 2; ++fj) {
    const int col = j0 + fj * 16 + lr;
    const float br  = bih[col] + bhh[col];
    const float bz  = bih[HD + col] + bhh[HD + col];
    const float bin = bih[2 * HD + col];
    const float bhn = bhh[2 * HD + col];
    const int rbase = m0 + wave * 16 + lk * 4;
#pragma unroll
    for (int q = 0; q < 4; ++q) {
      const int row = rbase + q;
      const float r = sigmoidf_(acc[fj][0][q] + br);
      const float z = sigmoidf_(acc[fj][1][q] + bz);
      const float n = tanhf(acc[fj][2][q] + bin + r * (acc[fj][3][q] + bhn));
      const float hv = (1.0f - z) * n + z * Hin[(size_t)row * HD + col];
      Hout[(size_t)row * HD + col]  = hv;
      HoutB[(size_t)row * HD + col] = f2b(hv);
    }
  }
}

// ---------------- bf16 NT GEMM v3 (counted-vmcnt pipeline) ----------------
// O[M,N] = A[M,K] @ W[N,K]^T + bias; tile 64x64, 256 thr, 4 gload_lds/stage.
__global__ __launch_bounds__(256, 2)
void gemm_nt3(const bf16_t* __restrict__ A, int lda, int K,
              const bf16_t* __restrict__ W, int ldw,
              const float* __restrict__ bias,
              float* __restrict__ O, int ldo, int N,
              bf16_t* __restrict__ OB, int ldob)
{
  __shared__ bf16_t aT[2][64 * 64];
  __shared__ bf16_t bT[2][64 * 64];
  const int tid = threadIdx.x, wave = tid >> 6, lane = tid & 63;
  const int m0 = blockIdx.y * 64, n0 = blockIdx.x * 64;
  const int wm = wave & 1, wn = wave >> 1;
  const int lr = lane & 15, lk = lane >> 4;
  const int rl = lane >> 3, cl = (lane & 7) * 8;

  fx4 acc[2][2];
#pragma unroll
  for (int a = 0; a < 2; ++a)
#pragma unroll
    for (int b = 0; b < 2; ++b) acc[a][b] = fx4{0.f, 0.f, 0.f, 0.f};

  const bf16_t* pA[2]; const bf16_t* pB[2]; int slot[2];
#pragma unroll
  for (int i = 0; i < 2; ++i) {
    const int t = wave * 2 + i;
    const int r = t * 8 + rl;
    const int c = cl ^ ((r & 7) * 8);
    pA[i] = A + (size_t)(m0 + r) * lda + c;
    pB[i] = W + (size_t)(n0 + r) * ldw + c;
    slot[i] = t * 512;
  }
  int aRow[2], bRow[2], ko[2];
#pragma unroll
  for (int f = 0; f < 2; ++f) {
    aRow[f] = (wm * 32 + f * 16 + lr) * 64;
    bRow[f] = (wn * 32 + f * 16 + lr) * 64;
  }
#pragma unroll
  for (int h = 0; h < 2; ++h) ko[h] = (h * 32 + lk * 8) ^ ((lr & 7) * 8);

  auto stage = [&](int buf, int kb) {
#pragma unroll
    for (int i = 0; i < 2; ++i) {
      gload16(pA[i] + kb, &aT[buf][slot[i]]);
      gload16(pB[i] + kb, &bT[buf][slot[i]]);
    }
  };

  const int nk = K >> 6;
  stage(0, 0);
  stage(1, 64);
  for (int s = 0; s < nk; ++s) {
    if (s == nk - 1) wait_vm0(); else wait_vm4();
    __builtin_amdgcn_s_barrier();
    const bf16_t* aB = &aT[s & 1][0];
    const bf16_t* bB = &bT[s & 1][0];
    bfx8 af[2][2], bfr[2][2];   // [f][h]
#pragma unroll
    for (int f = 0; f < 2; ++f)
#pragma unroll
      for (int h = 0; h < 2; ++h) {
        af[f][h]  = *reinterpret_cast<const bfx8*>(&aB[aRow[f] + ko[h]]);
        bfr[f][h] = *reinterpret_cast<const bfx8*>(&bB[bRow[f] + ko[h]]);
      }
    wait_lgkm0();
    __builtin_amdgcn_sched_barrier(0);
    __builtin_amdgcn_s_barrier();
    if (s + 2 < nk) stage(s & 1, (s + 2) << 6);
    __builtin_amdgcn_s_setprio(1);
#pragma unroll
    for (int h = 0; h < 2; ++h)
#pragma unroll
      for (int fm = 0; fm < 2; ++fm)
#pragma unroll
        for (int fj = 0; fj < 2; ++fj)
          acc[fm][fj] = __builtin_amdgcn_mfma_f32_16x16x32_bf16(af[fm][h], bfr[fj][h], acc[fm][fj], 0, 0, 0);
    __builtin_amdgcn_s_setprio(0);
  }

#pragma unroll
  for (int fm = 0; fm < 2; ++fm)
#pragma unroll
    for (int fj = 0; fj < 2; ++fj) {
      const int col = n0 + wn * 32 + fj * 16 + lr;
      if (col < N) {
        const float bb = bias[col];
#pragma unroll
        for (int q = 0; q < 4; ++q) {
          const int row = m0 + wm * 32 + fm * 16 + lk * 4 + q;
          const float v = acc[fm][fj][q] + bb;
          O[(size_t)row * ldo + col] = v;
          if (OB) OB[(size_t)row * ldob + col] = f2b(v);
        }
      }
    }
}

// ---------------- z build (writes bf16) ----------------
__global__ void build_zb(const float* __restrict__ mu, const float* __restrict__ lv,
                         const float* __restrict__ eps, const float* __restrict__ genre,
                         bf16_t* __restrict__ zb) {
  int i = blockIdx.x * 256 + threadIdx.x;
  int b = i >> 10, c = i & 1023;
  float v;
  if (c < LATM) {
    size_t k = (size_t)b * LATM + c;
    v = mu[k] + expf(0.5f * lv[k]) * eps[k];
  } else {
    v = genre[b * NGENRE + (c - LATM)];
  }
  zb[i] = f2b(v);
}

// ================= fp32 fallback =================
__global__ __launch_bounds__(256, 1)
void gru_stepF(const float* __restrict__ A1, int lda1, int K1,
               const float* __restrict__ Wih,
               const float* __restrict__ Hin,
               const float* __restrict__ Whh,
               const float* __restrict__ bih, const float* __restrict__ bhh,
               float* __restrict__ Hout)
{
  __shared__ bf16_t a_lds[128][32];
  __shared__ bf16_t b_lds[96][32];
  const int tid = threadIdx.x, wave = tid >> 6, lane = tid & 63;
  const int m0 = (blockIdx.x >> 6) * 128, j0 = (blockIdx.x & 63) * 32;
  const int lr = lane & 15, lk = lane >> 4;
  fx4 acc[2][2][4];
#pragma unroll
  for (int a = 0; a < 2; ++a)
#pragma unroll
    for (int b = 0; b < 2; ++b)
#pragma unroll
      for (int g = 0; g < 4; ++g) acc[a][b][g] = fx4{0.f, 0.f, 0.f, 0.f};

  for (int ph = 0; ph < 2; ++ph) {
    const float* Ag = ph ? Hin : A1;
    const int lda = ph ? HD : lda1, kLen = ph ? HD : K1;
    const float* W = ph ? Whh : Wih;
    const int nslot = ph ? 3 : 2;
    const int nkk = (kLen + 31) >> 5;
    for (int s = 0; s < nkk; ++s) {
      const int kb = s << 5;
#pragma unroll
      for (int it = 0; it < 16; ++it) {
        int i = tid + it * 256;
        int r = i >> 5, kk = i & 31, gk = kb + kk;
        float v = 0.0f;
        if (Ag && gk < kLen) v = Ag[(size_t)(m0 + r) * lda + gk];
        a_lds[r][kk] = f2b(v);
      }
#pragma unroll
      for (int it = 0; it < 12; ++it) {
        int i = tid + it * 256;
        int r = i >> 5, kk = i & 31, g = r >> 5, jj = r & 31, gk = kb + kk;
        b_lds[r][kk] = (gk < kLen) ? f2b(W[(size_t)(g * HD + j0 + jj) * kLen + gk]) : f2b(0.0f);
      }
      __syncthreads();
      bfx8 af[2];
#pragma unroll
      for (int fm = 0; fm < 2; ++fm)
        af[fm] = *reinterpret_cast<const bfx8*>(&a_lds[wave * 32 + fm * 16 + lr][lk * 8]);
#pragma unroll
      for (int g = 0; g < 3; ++g) {
        const int slot = (g == 2) ? nslot : g;
#pragma unroll
        for (int fj = 0; fj < 2; ++fj) {
          bfx8 bfr = *reinterpret_cast<const bfx8*>(&b_lds[g * 32 + fj * 16 + lr][lk * 8]);
#pragma unroll
          for (int fm = 0; fm < 2; ++fm)
            acc[fm][fj][slot] = __builtin_amdgcn_mfma_f32_16x16x32_bf16(af[fm], bfr, acc[fm][fj][slot], 0, 0, 0);
        }
      }
      __syncthreads();
    }
  }
#pragma unroll
  for (int fj = 0; fj < 2; ++fj) {
    const int col = j0 + fj * 16 + lr;
    const float br = bih[col] + bhh[col];
    const float bz = bih[HD + col] + bhh[HD + col];
    const float bin = bih[2 * HD + col];
    const float bhn = bhh[2 * HD + col];
#pragma unroll
    for (int fm = 0; fm < 2; ++fm) {
      const int rbase = m0 + wave * 32 + fm * 16 + lk * 4;
#pragma unroll
      for (int q = 0; q < 4; ++q) {
        const int row = rbase + q;
        const float r = sigmoidf_(acc[fm][fj][0][q] + br);
        const float z = sigmoidf_(acc[fm][fj][1][q] + bz);
        const float n = tanhf(acc[fm][fj][2][q] + bin + r * (acc[fm][fj][3][q] + bhn));
        Hout[(size_t)row * HD + col] = (1.0f - z) * n + z * Hin[(size_t)row * HD + col];
      }
    }
  }
}

__global__ __launch_bounds__(256, 1)
void gemm_ntF(const float* __restrict__ A, int lda, int K,
              const float* __restrict__ W,
              const float* __restrict__ bias,
              float* __restrict__ O, int ldo, int N)
{
  __shared__ bf16_t a_lds[64][32];
  __shared__ bf16_t b_lds[64][32];
  const int tid = threadIdx.x, wave = tid >> 6, lane = tid & 63;
  const int m0 = blockIdx.y * 64, n0 = blockIdx.x * 64;
  const int wm = (wave & 1) * 32, wn = (wave >> 1) * 32;
  const int lr = lane & 15, lk = lane >> 4;
  fx4 acc[2][2];
#pragma unroll
  for (int a = 0; a < 2; ++a)
#pragma unroll
    for (int b = 0; b < 2; ++b) acc[a][b] = fx4{0.f, 0.f, 0.f, 0.f};
  for (int kb = 0; kb < K; kb += 32) {
#pragma unroll
    for (int it = 0; it < 8; ++it) {
      int i = tid + it * 256;
      int r = i >> 5, kk = i & 31;
      a_lds[r][kk] = f2b(A[(size_t)(m0 + r) * lda + kb + kk]);
    }
#pragma unroll
    for (int it = 0; it < 8; ++it) {
      int i = tid + it * 256;
      int r = i >> 5, kk = i & 31;
      int n = n0 + r;
      b_lds[r][kk] = (n < N) ? f2b(W[(size_t)n * K + kb + kk]) : f2b(0.0f);
    }
    __syncthreads();
    bfx8 af[2], bfr[2];
#pragma unroll
    for (int f = 0; f < 2; ++f) {
      af[f] = *reinterpret_cast<const bfx8*>(&a_lds[wm + f * 16 + lr][lk * 8]);
      bfr[f] = *reinterpret_cast<const bfx8*>(&b_lds[wn + f * 16 + lr][lk * 8]);
    }
#pragma unroll
    for (int fm = 0; fm < 2; ++fm)
#pragma unroll
      for (int fj = 0; fj < 2; ++fj)
        acc[fm][fj] = __builtin_amdgcn_mfma_f32_16x16x32_bf16(af[fm], bfr[fj], acc[fm][fj], 0, 0, 0);
    __syncthreads();
  }
#pragma unroll
  for (int fm = 0; fm < 2; ++fm)
#pragma unroll
    for (int fj = 0; fj < 2; ++fj) {
      const int col = n0 + wn + fj * 16 + lr;
      if (col < N) {
        const float bb = bias[col];
#pragma unroll
        for (int q = 0; q < 4; ++q) {
          const int row = m0 + wm + fm * 16 + lk * 4 + q;
          O[(size_t)row * ldo + col] = acc[fm][fj][q] + bb;
        }
      }
    }
}

__global__ void build_zf(const float* __restrict__ mu, const float* __restrict__ lv,
                         const float* __restrict__ eps, const float* __restrict__ genre,
                         float* __restrict__ z) {
  int i = blockIdx.x * 256 + threadIdx.x;
  int b = i >> 10, c = i & 1023;
  z[i] = (c < LATM) ? mu[(size_t)b * LATM + c] + expf(0.5f * lv[(size_t)b * LATM + c]) * eps[(size_t)b * LATM + c]
                    : genre[b * NGENRE + (c - LATM)];
}

// ---------------- host ----------------
extern "C" void kernel_launch(void* const* d_in, const int* in_sizes, int n_in,
                              void* d_out, int out_size, void* d_ws, size_t ws_size,
                              hipStream_t stream) {
  const float* x      = (const float*)d_in[0];
  const float* genre  = (const float*)d_in[1];
  const float* eps    = (const float*)d_in[2];
  const float* eWih   = (const float*)d_in[3];
  const float* eWhh   = (const float*)d_in[4];
  const float* eBih   = (const float*)d_in[5];
  const float* eBhh   = (const float*)d_in[6];
  const float* dWih   = (const float*)d_in[7];
  const float* dWhh   = (const float*)d_in[8];
  const float* dBih   = (const float*)d_in[9];
  const float* dBhh   = (const float*)d_in[10];
  const float* fcMuW  = (const float*)d_in[11];
  const float* fcMuB  = (const float*)d_in[12];
  const float* fcLvW  = (const float*)d_in[13];
  const float* fcLvB  = (const float*)d_in[14];
  const float* fcOutW = (const float*)d_in[15];
  const float* fcOutB = (const float*)d_in[16];
  const float* fcDecW = (const float*)d_in[17];
  const float* fcDecB = (const float*)d_in[18];

  float* out = (float*)d_out;
  float* muO = out + (size_t)TT * BB * INDIM;
  float* lvO = muO + (size_t)BB * LATM;

  const size_t nEih = (size_t)3 * HD * XKP;
  const size_t nEhh = (size_t)3 * HD * HD;
  const size_t nDih = (size_t)3 * HD * INDIM;
  const size_t nDhh = (size_t)3 * HD * HD;
  const size_t nMu  = (size_t)1024 * HD;
  const size_t nOut = (size_t)HD * LATD;
  const size_t nDec = (size_t)INDIM * HD;
  const size_t oEih = 0;
  const size_t oEhh = oEih + nEih;
  const size_t oDih = oEhh + nEhh;
  const size_t oDhh = oDih + nDih;
  const size_t oMu  = oDhh + nDhh;
  const size_t oLv  = oMu + nMu;
  const size_t oOut = oLv + nMu;
  const size_t oDec = oOut + nOut;
  const size_t wTot = oDec + nDec;

  const size_t bytesW  = wTot * 2;
  const size_t bytesHF = (size_t)BB * HD * 4;
  const size_t bytesHB = (size_t)BB * HD * 2;
  const size_t bytesZB = (size_t)BB * LATD * 2;
  const size_t bytesNB = (size_t)BB * INDIM * 2;
  const size_t bytesX1 = (size_t)BB * XKP * 2;            // per-step x buffer
  const size_t bytesXB = (size_t)TT * BB * XKP * 2;       // full x precast
  const size_t needB = bytesW + 2 * bytesHF + 2 * bytesHB + bytesZB + bytesNB + bytesX1 + 1024;
  const size_t needA = needB + bytesXB;

  if (ws_size >= needB) {
    const bool haveXB = (ws_size >= needA);
    char* p = (char*)d_ws;
    bf16_t* wb = (bf16_t*)p;            p += bytesW;
    float* h0  = (float*)p;             p += bytesHF;
    float* h1  = (float*)p;             p += bytesHF;
    bf16_t* hb0 = (bf16_t*)p;           p += bytesHB;
    bf16_t* hb1 = (bf16_t*)p;           p += bytesHB;
    bf16_t* zb  = (bf16_t*)p;           p += bytesZB;
    bf16_t* nb  = (bf16_t*)p;           p += bytesNB;
    bf16_t* x1  = (bf16_t*)p;           p += bytesX1;
    bf16_t* xb  = haveXB ? (bf16_t*)p : nullptr;

    auto cast = [&](const float* s, bf16_t* d, int rs, int rp, int K, int ldp) {
      int g = rp > 8192 ? 8192 : rp;
      wcast_pad<<<g, 256, 0, stream>>>(s, d, rs, rp, K, ldp);
    };
    cast(eWih,   wb + oEih, 3 * HD, 3 * HD, XK,    XKP);
    cast(eWhh,   wb + oEhh, 3 * HD, 3 * HD, HD,    HD);
    cast(dWih,   wb + oDih, 3 * HD, 3 * HD, INDIM, INDIM);
    cast(dWhh,   wb + oDhh, 3 * HD, 3 * HD, HD,    HD);
    cast(fcMuW,  wb + oMu,  LATM,   1024,   HD,    HD);
    cast(fcLvW,  wb + oLv,  LATM,   1024,   HD,    HD);
    cast(fcOutW, wb + oOut, HD,     HD,     LATD,  LATD);
    cast(fcDecW, wb + oDec, INDIM,  INDIM,  HD,    HD);
    if (haveXB) cast(x, xb, TT * BB, TT * BB, XK, XKP);

    hipMemsetAsync(h0, 0, bytesHF, stream);
    hipMemsetAsync(hb0, 0, bytesHB, stream);

    float*  hF[2] = {h0, h1};
    bf16_t* hB[2] = {hb0, hb1};

    // ---- encoder ----
    for (int t = 0; t < TT; ++t) {
      const int ci = t & 1, co = ci ^ 1;
      const bf16_t* xt;
      if (haveXB) {
        xt = xb + (size_t)t * BB * XKP;
      } else {
        wcast_pad<<<512, 256, 0, stream>>>(x + (size_t)t * BB * XK, x1, BB, BB, XK, XKP);
        xt = x1;
      }
      gru3<<<512, 256, 0, stream>>>(xt, XKP, XKP / 64,
                                    wb + oEih, XKP, hB[ci], wb + oEhh,
                                    hF[ci], eBih, eBhh, hF[co], hB[co]);
    }
    // h_enc = hF[0]/hB[0]
    gemm_nt3<<<dim3(16, 8), 256, 0, stream>>>(hB[0], HD, HD, wb + oMu, HD, fcMuB,
                                              muO, LATM, LATM, nullptr, 0);
    gemm_nt3<<<dim3(16, 8), 256, 0, stream>>>(hB[0], HD, HD, wb + oLv, HD, fcLvB,
                                              lvO, LATM, LATM, nullptr, 0);
    build_zb<<<(BB * LATD) / 256, 256, 0, stream>>>(muO, lvO, eps, genre, zb);
    gemm_nt3<<<dim3(32, 8), 256, 0, stream>>>(zb, LATD, LATD, wb + oOut, LATD, fcOutB,
                                              hF[0], HD, HD, hB[0], HD);
    // ---- decoder ----
    for (int t = 0; t < TT; ++t) {
      const int ci = t & 1, co = ci ^ 1;
      gru3<<<512, 256, 0, stream>>>(t ? nb : (const bf16_t*)nullptr, INDIM,
                                    t ? INDIM / 64 : 0,
                                    wb + oDih, INDIM, hB[ci], wb + oDhh,
                                    hF[ci], dBih, dBhh, hF[co], hB[co]);
      gemm_nt3<<<dim3(8, 8), 256, 0, stream>>>(hB[co], HD, HD, wb + oDec, HD, fcDecB,
                                               out + (size_t)t * BB * INDIM, INDIM, INDIM,
                                               nb, INDIM);
    }
  } else {
    // ---- fp32 fallback ----
    float* h0 = (float*)d_ws;
    float* h1 = h0 + (size_t)BB * HD;
    float* zb = h1 + (size_t)BB * HD;
    hipMemsetAsync(h0, 0, (size_t)BB * HD * sizeof(float), stream);
    float* hF[2] = {h0, h1};
    for (int t = 0; t < TT; ++t) {
      const int ci = t & 1, co = ci ^ 1;
      gru_stepF<<<256, 256, 0, stream>>>(x + (size_t)t * BB * XK, XK, XK, eWih,
                                         hF[ci], eWhh, eBih, eBhh, hF[co]);
    }
    gemm_ntF<<<dim3(16, 8), 256, 0, stream>>>(hF[0], HD, HD, fcMuW, fcMuB, muO, LATM, LATM);
    gemm_ntF<<<dim3(16, 8), 256, 0, stream>>>(hF[0], HD, HD, fcLvW, fcLvB, lvO, LATM, LATM);
    build_zf<<<(BB * LATD) / 256, 256, 0, stream>>>(muO, lvO, eps, genre, zb);
    gemm_ntF<<<dim3(32, 8), 256, 0, stream>>>(zb, LATD, LATD, fcOutW, fcOutB, hF[0], HD, HD);
    for (int t = 0; t < TT; ++t) {
      const int ci = t & 1, co = ci ^ 1;
      gru_stepF<<<256, 256, 0, stream>>>(t ? out + (size_t)(t - 1) * BB * INDIM : nullptr,
                                         INDIM, INDIM, dWih, hF[ci], dWhh, dBih, dBhh, hF[co]);
      gemm_ntF<<<dim3(8, 8), 256, 0, stream>>>(hF[co], HD, HD, fcDecW, fcDecB,
                                               out + (size_t)t * BB * INDIM, INDIM, INDIM);
    }
  }
  (void)in_sizes; (void)n_in; (void)out_size;
}